// Round 1
// 93.937 us; speedup vs baseline: 1.0526x; 1.0526x over previous
//
#include <hip/hip_runtime.h>

#define NX   192
#define NXY  (NX * NX)
#define LW   64              // lanes per row: one full wave per y-row
#define YB   4               // y rows (waves) per block
#define ZC   12              // z outputs per block (was 6: halo cost 8/6 -> 14/12)
#define NTH  (LW * YB)       // 256 threads = 4 waves
#define GY   (NX / YB)       // 48
#define GZ   (NX / ZC)       // 16
#define NBLK (GY * GZ)       // 768 = exactly 3 blocks/CU on 256 CUs, no tail

// 12-byte, 4-aligned row fragment (HIP float3 may be padded/align-16; this
// guarantees a dwordx3-style load with no OOB 16B read at the row tail).
struct f3 { float x, y, z; };

static __device__ __forceinline__ float frcp(float x) {
#if __has_builtin(__builtin_amdgcn_rcpf)
    return __builtin_amdgcn_rcpf(x);
#else
    return 1.f / x;
#endif
}

// 5 column stats (x0-1 .. x0+3) -> 3 x-window sums (outputs x0..x0+2)
#define WIN3(n, c0, c1, c2, c3, c4)  \
    n.x = (c0) + (c1) + (c2);        \
    n.y = (c1) + (c2) + (c3);        \
    n.z = (c2) + (c3) + (c4);

#define NCCC(o)                                                            \
    {                                                                      \
        const float Is  = p0I.o  + p1I.o  + nI.o;                          \
        const float Js  = p0J.o  + p1J.o  + nJ.o;                          \
        const float IIs = p0II.o + p1II.o + nII.o;                         \
        const float JJs = p0JJ.o + p1JJ.o + nJJ.o;                         \
        const float IJs = p0IJ.o + p1IJ.o + nIJ.o;                         \
        const float uI = Is * inv27;                                       \
        const float uJ = Js * inv27;                                       \
        const float cross = fmaf(-uJ, Is, IJs);                            \
        const float Iv    = fmaf(-uI, Is, IIs);                            \
        const float Jv    = fmaf(-uJ, Js, JJs);                            \
        const float den   = fmaf(Iv, Jv, 1e-5f);                           \
        acc.o = fmaf(cross * cross, frcp(den), acc.o);                     \
    }

// one masked row's contribution to the 5 column stats (cols x0-1..x0+3)
#define ROWACC3(aLs, av, aRs, bLs, bv, bRs, Mr, emr, epr)                  \
    {                                                                      \
        const float ax0 = (aLs) * (emr), ax1 = av.x * (Mr);                \
        const float ax2 = av.y * (Mr),   ax3 = av.z * (Mr);                \
        const float ax4 = (aRs) * (epr);                                   \
        const float bx0 = (bLs) * (emr), bx1 = bv.x * (Mr);                \
        const float bx2 = bv.y * (Mr),   bx3 = bv.z * (Mr);                \
        const float bx4 = (bRs) * (epr);                                   \
        cI0 += ax0; cI1 += ax1; cI2 += ax2; cI3 += ax3; cI4 += ax4;        \
        cJ0 += bx0; cJ1 += bx1; cJ2 += bx2; cJ3 += bx3; cJ4 += bx4;        \
        cII0 = fmaf(ax0, ax0, cII0); cII1 = fmaf(ax1, ax1, cII1);          \
        cII2 = fmaf(ax2, ax2, cII2); cII3 = fmaf(ax3, ax3, cII3);          \
        cII4 = fmaf(ax4, ax4, cII4);                                       \
        cJJ0 = fmaf(bx0, bx0, cJJ0); cJJ1 = fmaf(bx1, bx1, cJJ1);          \
        cJJ2 = fmaf(bx2, bx2, cJJ2); cJJ3 = fmaf(bx3, bx3, cJJ3);          \
        cJJ4 = fmaf(bx4, bx4, cJJ4);                                       \
        cIJ0 = fmaf(ax0, bx0, cIJ0); cIJ1 = fmaf(ax1, bx1, cIJ1);          \
        cIJ2 = fmaf(ax2, bx2, cIJ2); cIJ3 = fmaf(ax3, bx3, cIJ3);          \
        cIJ4 = fmaf(ax4, bx4, cIJ4);                                       \
    }

// One z-slice. 64 lanes x 3 outputs = 192 cols, ZERO idle lanes (previous
// version: 48 active / 16 masked-idle lanes = 25% wasted wave issue).
// Left halo col 3k-1 = lane(k-1).z via shfl_up; right halo 3k+3 = lane(k+1).x
// via shfl_down; k=0 / k=63 edges mask-zeroed (volume zero padding).
#define DO_SLICE(ZB, M0, M1, M2, EMIT)                                     \
    {                                                                      \
        const float* pz = pred + (ZB);                                     \
        const float* tz = targ + (ZB);                                     \
        const f3 a0 = *(const f3*)(pz + off0);                             \
        const f3 b0 = *(const f3*)(tz + off0);                             \
        const f3 a1 = *(const f3*)(pz + off1);                             \
        const f3 b1 = *(const f3*)(tz + off1);                             \
        const f3 a2 = *(const f3*)(pz + off2);                             \
        const f3 b2 = *(const f3*)(tz + off2);                             \
        const float aL0 = __shfl_up(a0.z, 1), aR0 = __shfl_down(a0.x, 1);  \
        const float bL0 = __shfl_up(b0.z, 1), bR0 = __shfl_down(b0.x, 1);  \
        const float aL1 = __shfl_up(a1.z, 1), aR1 = __shfl_down(a1.x, 1);  \
        const float bL1 = __shfl_up(b1.z, 1), bR1 = __shfl_down(b1.x, 1);  \
        const float aL2 = __shfl_up(a2.z, 1), aR2 = __shfl_down(a2.x, 1);  \
        const float bL2 = __shfl_up(b2.z, 1), bR2 = __shfl_down(b2.x, 1);  \
        const float M0_ = (M0), M1_ = (M1), M2_ = (M2);                    \
        const float em0 = M0_ * mxm, ep0 = M0_ * mxp;                      \
        const float em1 = M1_ * mxm, ep1 = M1_ * mxp;                      \
        const float em2 = M2_ * mxm, ep2 = M2_ * mxp;                      \
        float cI0 = 0.f, cI1 = 0.f, cI2 = 0.f, cI3 = 0.f, cI4 = 0.f;       \
        float cJ0 = 0.f, cJ1 = 0.f, cJ2 = 0.f, cJ3 = 0.f, cJ4 = 0.f;       \
        float cII0 = 0.f, cII1 = 0.f, cII2 = 0.f, cII3 = 0.f, cII4 = 0.f;  \
        float cJJ0 = 0.f, cJJ1 = 0.f, cJJ2 = 0.f, cJJ3 = 0.f, cJJ4 = 0.f;  \
        float cIJ0 = 0.f, cIJ1 = 0.f, cIJ2 = 0.f, cIJ3 = 0.f, cIJ4 = 0.f;  \
        ROWACC3(aL0, a0, aR0, bL0, b0, bR0, M0_, em0, ep0)                 \
        ROWACC3(aL1, a1, aR1, bL1, b1, bR1, M1_, em1, ep1)                 \
        ROWACC3(aL2, a2, aR2, bL2, b2, bR2, M2_, em2, ep2)                 \
        f3 nI, nJ, nII, nJJ, nIJ;                                          \
        WIN3(nI,  cI0,  cI1,  cI2,  cI3,  cI4)                             \
        WIN3(nJ,  cJ0,  cJ1,  cJ2,  cJ3,  cJ4)                             \
        WIN3(nII, cII0, cII1, cII2, cII3, cII4)                            \
        WIN3(nJJ, cJJ0, cJJ1, cJJ2, cJJ3, cJJ4)                            \
        WIN3(nIJ, cIJ0, cIJ1, cIJ2, cIJ3, cIJ4)                            \
        if (EMIT) { NCCC(x) NCCC(y) NCCC(z) }                              \
        p0I = p1I; p0J = p1J; p0II = p1II; p0JJ = p1JJ; p0IJ = p1IJ;       \
        p1I = nI;  p1J = nJ;  p1II = nII;  p1JJ = nJJ;  p1IJ = nIJ;        \
    }

// Register-only LNCC, branchless hot path, wave-aligned rows (64 lanes/row,
// ALL active: 3 x-outputs per lane). ZC=12 cuts z-halo work 8/6 -> 14/12 and
// issued bytes/output by 33%; grid = 768 = exactly 3 blocks/CU (launch_bounds
// (256,3) caps VGPR ~170 so all 3 stay resident). Two-kernel reduction kept
// (round 11: fused atomic+fence reduction costs ~48 us tail).
__global__ __launch_bounds__(NTH, 3)
void lncc_main(const float* __restrict__ pred, const float* __restrict__ targ,
               double* __restrict__ partial) {
    __shared__ float wred[NTH / 64];

    // XCD-aware bijective swizzle (NBLK % 8 == 0): each XCD gets 96
    // consecutive workgroups = 2 full z-slabs, so y/z halo rows shared by
    // neighbor blocks hit the same XCD's L2 instead of round-robin L3.
    const int bid = blockIdx.x;
    const int wg  = (bid & 7) * (NBLK / 8) + (bid >> 3);
    const int by  = wg % GY;
    const int bz  = wg / GY;

    const int k  = threadIdx.x;            // 0..63, all lanes active
    const int x0 = 3 * k;                  // 64 lanes x 3 outputs = 192 cols
    const int y  = by * YB + threadIdx.y;
    const int z0 = bz * ZC;

    // pre-clamped row offsets (always in-bounds)
    const int ym = (y > 0) ? y - 1 : 0;
    const int yp = (y < NX - 1) ? y + 1 : y;
    const int off0 = ym * NX + x0;
    const int off1 = y  * NX + x0;
    const int off2 = yp * NX + x0;

    // 0/1 masks for the padding contributions
    const float fm0 = (y > 0) ? 1.f : 0.f;
    const float fm2 = (y < NX - 1) ? 1.f : 0.f;
    const float mxm = (k > 0) ? 1.f : 0.f;        // col 3k-1 = -1 at lane 0
    const float mxp = (k < LW - 1) ? 1.f : 0.f;   // col 3k+3 = 192 at lane 63
    const float zmA = (z0 > 0) ? 1.f : 0.f;
    const float zmB = (z0 + ZC < NX) ? 1.f : 0.f;
    const int   zb0 = ((z0 > 0) ? z0 - 1 : 0) * NXY;
    const int   zbL = ((z0 + ZC < NX) ? z0 + ZC : NX - 1) * NXY;

    const float inv27 = 1.f / 27.f;
    const f3 zero3 = {0.f, 0.f, 0.f};
    f3 p0I = zero3, p0J = zero3, p0II = zero3, p0JJ = zero3, p0IJ = zero3;
    f3 p1I = zero3, p1J = zero3, p1II = zero3, p1JJ = zero3, p1IJ = zero3;
    f3 acc = zero3;

    // 14-step schedule: slice z = z0-1+s; emit for s>=2 (output z0+s-2)
    DO_SLICE(zb0,             fm0 * zmA, zmA, fm2 * zmA, 0)   // s=0
    DO_SLICE((z0      ) * NXY, fm0, 1.f, fm2, 0)              // s=1
    DO_SLICE((z0 +  1) * NXY, fm0, 1.f, fm2, 1)               // s=2
    DO_SLICE((z0 +  2) * NXY, fm0, 1.f, fm2, 1)               // s=3
    DO_SLICE((z0 +  3) * NXY, fm0, 1.f, fm2, 1)               // s=4
    DO_SLICE((z0 +  4) * NXY, fm0, 1.f, fm2, 1)               // s=5
    DO_SLICE((z0 +  5) * NXY, fm0, 1.f, fm2, 1)               // s=6
    DO_SLICE((z0 +  6) * NXY, fm0, 1.f, fm2, 1)               // s=7
    DO_SLICE((z0 +  7) * NXY, fm0, 1.f, fm2, 1)               // s=8
    DO_SLICE((z0 +  8) * NXY, fm0, 1.f, fm2, 1)               // s=9
    DO_SLICE((z0 +  9) * NXY, fm0, 1.f, fm2, 1)               // s=10
    DO_SLICE((z0 + 10) * NXY, fm0, 1.f, fm2, 1)               // s=11
    DO_SLICE((z0 + 11) * NXY, fm0, 1.f, fm2, 1)               // s=12
    DO_SLICE(zbL,             fm0 * zmB, zmB, fm2 * zmB, 1)   // s=13

    // ---- block reduction -> one double partial per block ----
    float v = acc.x + acc.y + acc.z;
#pragma unroll
    for (int off = 32; off > 0; off >>= 1) v += __shfl_down(v, off);
    const int tid = threadIdx.y * LW + threadIdx.x;
    if ((tid & 63) == 0) wred[tid >> 6] = v;
    __syncthreads();
    if (tid == 0) {
        double t = 0.0;
#pragma unroll
        for (int i = 0; i < NTH / 64; ++i) t += (double)wred[i];
        partial[bid] = t;
    }
}

__global__ __launch_bounds__(256)
void lncc_reduce(const double* __restrict__ partial, float* __restrict__ out) {
    __shared__ double dred[4];
    double sum = 0.0;
    for (int i = threadIdx.x; i < NBLK; i += 256) sum += partial[i];
#pragma unroll
    for (int off = 32; off > 0; off >>= 1) sum += __shfl_down(sum, off);
    if ((threadIdx.x & 63) == 0) dred[threadIdx.x >> 6] = sum;
    __syncthreads();
    if (threadIdx.x == 0) {
        const double n = (double)NX * NX * NX;
        out[0] = (float)(-(dred[0] + dred[1] + dred[2] + dred[3]) / n);
    }
}

extern "C" void kernel_launch(void* const* d_in, const int* in_sizes, int n_in,
                              void* d_out, int out_size, void* d_ws, size_t ws_size,
                              hipStream_t stream) {
    const float* pred = (const float*)d_in[0];
    const float* targ = (const float*)d_in[1];
    double* partial = (double*)d_ws;
    float* out = (float*)d_out;

    dim3 grid(NBLK);                      // 768 blocks, 1D for XCD swizzle
    dim3 block(LW, YB);                   // 64 x 4 = 256 threads (4 waves)
    lncc_main<<<grid, block, 0, stream>>>(pred, targ, partial);
    lncc_reduce<<<1, 256, 0, stream>>>(partial, out);
}